// Round 5
// baseline (734.730 us; speedup 1.0000x reference)
//
#include <hip/hip_runtime.h>

// Problem constants: B=64, T=256, V=4096, H=512
// Inputs: x[B*T] i32, Wxh[V,H] f32, Whh[H,H] f32, bh[H] f32, Wo[H,V] f32, Bo[V] f32
// Output: out[B,T,V] f32 = (scan hs) @ Wo + Bo

typedef __fp16 half2_t __attribute__((ext_vector_type(2)));  // clang builtin half type
typedef __attribute__((ext_vector_type(8))) short short8;   // 8 bf16 = 4 VGPRs (MFMA A/B frag)
typedef __attribute__((ext_vector_type(4))) float f32x4;    // MFMA C/D frag

__device__ __forceinline__ unsigned short f32_to_bf16(float f) {
  unsigned int u = __builtin_bit_cast(unsigned int, f);
  u = (u + 0x7FFFu + ((u >> 16) & 1u)) >> 16;  // RNE
  return (unsigned short)u;
}

__device__ __forceinline__ unsigned int pack_f16x2(float a, float b) {
  half2_t h = __builtin_amdgcn_cvt_pkrtz(a, b);  // v_cvt_pkrtz_f16_f32
  return __builtin_bit_cast(unsigned int, h);
}

__device__ __forceinline__ float fdot2_(unsigned int w, unsigned int h, float acc) {
  return __builtin_amdgcn_fdot2(__builtin_bit_cast(half2_t, w),
                                __builtin_bit_cast(half2_t, h), acc, false);
}

__device__ __forceinline__ void glds16(const void* g, void* lds) {
  // async global->LDS, 16B per lane; lds must be wave-uniform base (dest = base + lane*16)
  __builtin_amdgcn_global_load_lds(
      (const __attribute__((address_space(1))) unsigned int*)g,
      (__attribute__((address_space(3))) unsigned int*)lds, 16, 0, 0);
}

// ---------------------------------------------------------------------------
// Prep 1: Whh [i][j] f32 -> WhhP2 u32 layout: flat idx = k4*2048 + j*4 + c
// packs pair k = 4*k4+c of column j, i.e. ((uint4*)WhhP2)[k4*512+j] holds
// h-pairs 4k4..4k4+3 (h elements 8k4..8k4+7) of column j.
// ---------------------------------------------------------------------------
__global__ __launch_bounds__(256) void pack_whh(const float* __restrict__ Whh,
                                                unsigned int* __restrict__ WhhP2) {
  int idx = blockIdx.x * 256 + threadIdx.x;  // 131072 total u32
  int c = idx & 3;
  int j = (idx >> 2) & 511;
  int k4 = idx >> 11;
  int k = k4 * 4 + c;  // pair index 0..255
  float f0 = Whh[(2 * k) * 512 + j];
  float f1 = Whh[(2 * k + 1) * 512 + j];
  WhhP2[idx] = pack_f16x2(f0, f1);
}

// ---------------------------------------------------------------------------
// Prep 2: Wo [h][v] f32 -> WoT [v][h] bf16 (transposed for MFMA B-frag reads)
// ---------------------------------------------------------------------------
__global__ __launch_bounds__(256) void transpose_wo(const float* __restrict__ Wo,
                                                    unsigned short* __restrict__ WoT) {
  __shared__ float tile[64][65];
  const int tv = blockIdx.x;   // 0..63  (V/64)
  const int th = blockIdx.y;   // 0..7   (H/64)
  const int tid = threadIdx.x;
  const int c = tid & 63, r4 = tid >> 6;
#pragma unroll
  for (int p = 0; p < 16; ++p) {
    int hl = p * 4 + r4;
    tile[hl][c] = Wo[(size_t)(th * 64 + hl) * 4096 + tv * 64 + c];  // coalesced read
  }
  __syncthreads();
#pragma unroll
  for (int p = 0; p < 16; ++p) {
    int vl = p * 4 + r4;
    WoT[(size_t)(tv * 64 + vl) * 512 + th * 64 + c] = f32_to_bf16(tile[c][vl]);  // coalesced write
  }
}

// ---------------------------------------------------------------------------
// Recurrence: one block per batch element, 512 threads (8 waves = 2/SIMD,
// VGPR cap 256). R2-R4 post-mortem: clang demotes large uint4 ARRAYS to
// scratch even with static indices (VGPR_Count stuck at 128). Fix: 32
// individually NAMED uint4 for the register-resident half (w0..w31) + two
// named 8-uint4 stream buffers (sa*, sb*) -- named live ranges don't get
// aggregate-demoted. Streamed half (pairs k4=32..63) re-read from L2 each
// step with one-chunk lookahead. h double-buffered in LDS, 1 barrier/step.
// ---------------------------------------------------------------------------
#define LOADW(i) const uint4 w##i = W4[(size_t)(i) * 512 + j]

#define DOT1(W, idx) do { const uint4 hp_ = hb[idx]; \
  a0 = fdot2_(W.x, hp_.x, a0); a1 = fdot2_(W.y, hp_.y, a1); \
  a2 = fdot2_(W.z, hp_.z, a2); a3 = fdot2_(W.w, hp_.w, a3); } while (0)

#define LDCH(B, c) do { const uint4* p_ = W4 + (size_t)(32 + (c) * 8) * 512 + j; \
  B##0 = p_[0 * 512]; B##1 = p_[1 * 512]; B##2 = p_[2 * 512]; B##3 = p_[3 * 512]; \
  B##4 = p_[4 * 512]; B##5 = p_[5 * 512]; B##6 = p_[6 * 512]; B##7 = p_[7 * 512]; \
} while (0)

#define DOTCH(B, c) do { \
  DOT1(B##0, 32 + (c) * 8 + 0); DOT1(B##1, 32 + (c) * 8 + 1); \
  DOT1(B##2, 32 + (c) * 8 + 2); DOT1(B##3, 32 + (c) * 8 + 3); \
  DOT1(B##4, 32 + (c) * 8 + 4); DOT1(B##5, 32 + (c) * 8 + 5); \
  DOT1(B##6, 32 + (c) * 8 + 6); DOT1(B##7, 32 + (c) * 8 + 7); \
} while (0)

__global__ __launch_bounds__(512, 2) void rnn_scan(const int* __restrict__ x,
                                                   const float* Wxh,
                                                   const unsigned int* WhhP2,
                                                   const float* __restrict__ bh,
                                                   unsigned short* hs) {
  __shared__ uint4 hbuf4[2][64];  // 2 x 512 h values as f16 pairs
  __shared__ int toks[256];
  const int b = blockIdx.x;
  const int j = threadIdx.x;  // 0..511
  const uint4* W4 = (const uint4*)WhhP2;

  // Register-resident pairs 0..127 (k4 = 0..31) of column j: 32 named uint4
  LOADW(0);  LOADW(1);  LOADW(2);  LOADW(3);  LOADW(4);  LOADW(5);  LOADW(6);  LOADW(7);
  LOADW(8);  LOADW(9);  LOADW(10); LOADW(11); LOADW(12); LOADW(13); LOADW(14); LOADW(15);
  LOADW(16); LOADW(17); LOADW(18); LOADW(19); LOADW(20); LOADW(21); LOADW(22); LOADW(23);
  LOADW(24); LOADW(25); LOADW(26); LOADW(27); LOADW(28); LOADW(29); LOADW(30); LOADW(31);

  if (j < 64) hbuf4[0][j] = make_uint4(0u, 0u, 0u, 0u);  // h0 = 0
  if (j < 256) toks[j] = x[b * 256 + j];
  const float bhj = bh[j];
  __syncthreads();

  unsigned short* hb16all = (unsigned short*)hbuf4;  // [2][512] u16 view

  for (int t = 0; t < 256; ++t) {
    asm volatile("" ::: "memory");  // block cross-iteration hoist/CSE of stream loads
    const int cur = t & 1;
    const uint4* hb = hbuf4[cur];
    const int tok = toks[t];

    uint4 sa0, sa1, sa2, sa3, sa4, sa5, sa6, sa7;
    uint4 sb0, sb1, sb2, sb3, sb4, sb5, sb6, sb7;
    LDCH(sa, 0);  // issue chunk 0 loads (k4 32..39)
    LDCH(sb, 1);  // issue chunk 1 loads (k4 40..47)

    const float xv = Wxh[(size_t)tok * 512 + j];  // L2/L3-hot row, coalesced

    float a0 = 0.f, a1 = 0.f, a2 = 0.f, a3 = 0.f;
    // register-resident half: L2 latency of chunks 0-1 hides under these dots
    DOT1(w0, 0);   DOT1(w1, 1);   DOT1(w2, 2);   DOT1(w3, 3);
    DOT1(w4, 4);   DOT1(w5, 5);   DOT1(w6, 6);   DOT1(w7, 7);
    DOT1(w8, 8);   DOT1(w9, 9);   DOT1(w10, 10); DOT1(w11, 11);
    DOT1(w12, 12); DOT1(w13, 13); DOT1(w14, 14); DOT1(w15, 15);
    DOT1(w16, 16); DOT1(w17, 17); DOT1(w18, 18); DOT1(w19, 19);
    DOT1(w20, 20); DOT1(w21, 21); DOT1(w22, 22); DOT1(w23, 23);
    DOT1(w24, 24); DOT1(w25, 25); DOT1(w26, 26); DOT1(w27, 27);
    DOT1(w28, 28); DOT1(w29, 29); DOT1(w30, 30); DOT1(w31, 31);
    // streamed half: consume chunk, refill buffer two chunks ahead
    DOTCH(sa, 0);
    LDCH(sa, 2);
    DOTCH(sb, 1);
    LDCH(sb, 3);
    DOTCH(sa, 2);
    DOTCH(sb, 3);

    const float u_ = xv + ((a0 + a1) + (a2 + a3)) + bhj;
    const float h = tanhf(u_);
    hs[(size_t)(b * 256 + t) * 512 + j] = f32_to_bf16(h);  // coalesced u16 store
    half2_t hp2 = __builtin_amdgcn_cvt_pkrtz(h, h);
    unsigned int hu = __builtin_bit_cast(unsigned int, hp2);
    hb16all[(cur ^ 1) * 512 + j] = (unsigned short)(hu & 0xFFFFu);  // write next buf
    __syncthreads();  // next buf visible; cur-buf reads all done -> safe to reuse
  }
}

// ---------------------------------------------------------------------------
// Output GEMM: C[16384,4096] = A[16384,512](bf16) @ WoT^T + Bo.
// m97 structure: 128x128 tile, BK=32, 256 thr (2x2 waves, 64x64 each),
// global_load_lds w16 staging, mfma_f32_16x16x32_bf16.
// ---------------------------------------------------------------------------
__global__ __launch_bounds__(256) void gemm_out(const unsigned short* __restrict__ A,
                                                const unsigned short* __restrict__ Bt,
                                                const float* __restrict__ Bo,
                                                float* __restrict__ C) {
  __shared__ alignas(16) unsigned short As[128 * 32];
  __shared__ alignas(16) unsigned short Bs[128 * 32];
  const int tid = threadIdx.x;
  const int lane = tid & 63, wid = tid >> 6;
  const int bn = blockIdx.x & 31, bm = blockIdx.x >> 5;
  const int wr = wid >> 1, wc = wid & 1;

  f32x4 acc[4][4] = {};

  // staging: thread covers row (tid>>2) of a 64-row pass, k-chunk (tid&3)*8
  const unsigned short* Ag = A + (size_t)(bm * 128 + (tid >> 2)) * 512 + (tid & 3) * 8;
  const unsigned short* Bg = Bt + (size_t)(bn * 128 + (tid >> 2)) * 512 + (tid & 3) * 8;
  char* AsW = (char*)As + wid * 1024;  // wave-uniform LDS dest
  char* BsW = (char*)Bs + wid * 1024;

  const int laneRow = lane & 15;
  const int k0 = (lane >> 4) * 8;

  for (int kt = 0; kt < 16; ++kt) {
    __syncthreads();  // previous compute done before overwrite
    const unsigned short* a0 = Ag + kt * 32;
    const unsigned short* b0 = Bg + kt * 32;
    glds16(a0,            AsW);
    glds16(a0 + 64 * 512, AsW + 4096);
    glds16(b0,            BsW);
    glds16(b0 + 64 * 512, BsW + 4096);
    __syncthreads();  // compiler drains vmcnt before barrier

    short8 af[4], bf[4];
#pragma unroll
    for (int f = 0; f < 4; ++f)
      af[f] = *(const short8*)&As[(wr * 64 + f * 16 + laneRow) * 32 + k0];
#pragma unroll
    for (int f = 0; f < 4; ++f)
      bf[f] = *(const short8*)&Bs[(wc * 64 + f * 16 + laneRow) * 32 + k0];
#pragma unroll
    for (int fm = 0; fm < 4; ++fm)
#pragma unroll
      for (int fn = 0; fn < 4; ++fn)
        acc[fm][fn] = __builtin_amdgcn_mfma_f32_16x16x32_bf16(af[fm], bf[fn], acc[fm][fn], 0, 0, 0);
  }

  // epilogue: C/D layout col=lane&15, row=(lane>>4)*4+reg  [m89-verified]
  const int mg0 = bm * 128 + wr * 64, ng0 = bn * 128 + wc * 64;
#pragma unroll
  for (int fn = 0; fn < 4; ++fn) {
    const int col = ng0 + fn * 16 + laneRow;
    const float bo = Bo[col];
#pragma unroll
    for (int fm = 0; fm < 4; ++fm) {
      const int row0 = mg0 + fm * 16 + (lane >> 4) * 4;
#pragma unroll
      for (int r = 0; r < 4; ++r)
        C[(size_t)(row0 + r) * 4096 + col] = acc[fm][fn][r] + bo;
    }
  }
}

// ---------------------------------------------------------------------------
extern "C" void kernel_launch(void* const* d_in, const int* in_sizes, int n_in,
                              void* d_out, int out_size, void* d_ws, size_t ws_size,
                              hipStream_t stream) {
  (void)in_sizes; (void)n_in; (void)out_size; (void)ws_size;
  const int* x = (const int*)d_in[0];
  const float* Wxh = (const float*)d_in[1];
  const float* Whh = (const float*)d_in[2];
  const float* bh = (const float*)d_in[3];
  const float* Wo = (const float*)d_in[4];
  const float* Bo = (const float*)d_in[5];
  float* out = (float*)d_out;

  // workspace: WhhP2 512KB | WoT 4MB | hs 16MB  (total 20.5 MB)
  unsigned int* WhhP2 = (unsigned int*)d_ws;
  unsigned short* WoT = (unsigned short*)((char*)d_ws + (512u << 10));
  unsigned short* hs = (unsigned short*)((char*)d_ws + (512u << 10) + (4u << 20));

  hipLaunchKernelGGL(pack_whh, dim3(512), dim3(256), 0, stream, Whh, WhhP2);
  hipLaunchKernelGGL(transpose_wo, dim3(64, 8), dim3(256), 0, stream, Wo, WoT);
  hipLaunchKernelGGL(rnn_scan, dim3(64), dim3(512), 0, stream, x, Wxh, WhhP2, bh, hs);
  hipLaunchKernelGGL(gemm_out, dim3(4096), dim3(256), 0, stream, hs, WoT, Bo, out);
}

// Round 6
// 680.970 us; speedup vs baseline: 1.0789x; 1.0789x over previous
//
#include <hip/hip_runtime.h>

// Problem constants: B=64, T=256, V=4096, H=512
// Inputs: x[B*T] i32, Wxh[V,H] f32, Whh[H,H] f32, bh[H] f32, Wo[H,V] f32, Bo[V] f32
// Output: out[B,T,V] f32 = (scan hs) @ Wo + Bo

typedef __fp16 half2_t __attribute__((ext_vector_type(2)));  // clang builtin half type
typedef __attribute__((ext_vector_type(8))) short short8;   // 8 bf16 = 4 VGPRs (MFMA A/B frag)
typedef __attribute__((ext_vector_type(4))) float f32x4;    // MFMA C/D frag

__device__ __forceinline__ unsigned short f32_to_bf16(float f) {
  unsigned int u = __builtin_bit_cast(unsigned int, f);
  u = (u + 0x7FFFu + ((u >> 16) & 1u)) >> 16;  // RNE
  return (unsigned short)u;
}

__device__ __forceinline__ unsigned int pack_f16x2(float a, float b) {
  half2_t h = __builtin_amdgcn_cvt_pkrtz(a, b);  // v_cvt_pkrtz_f16_f32
  return __builtin_bit_cast(unsigned int, h);
}

__device__ __forceinline__ float fdot2_(unsigned int w, unsigned int h, float acc) {
  return __builtin_amdgcn_fdot2(__builtin_bit_cast(half2_t, w),
                                __builtin_bit_cast(half2_t, h), acc, false);
}

__device__ __forceinline__ void glds16(const void* g, void* lds) {
  __builtin_amdgcn_global_load_lds(
      (const __attribute__((address_space(1))) unsigned int*)g,
      (__attribute__((address_space(3))) unsigned int*)lds, 16, 0, 0);
}

// ---------------------------------------------------------------------------
// Prep 1: Whh -> WhhP3.  uint4 at index U = (k4*4 + o)*128 + g holds f16
// pairs p = 4*k4+c (c = 0..3) of column j = o*128 + g.  Pair p = elements
// (2p, 2p+1).  Matches the scan's (g, i, o, chunk) decomposition so that
// consecutive g -> consecutive 16B -> coalesced.
// ---------------------------------------------------------------------------
__global__ __launch_bounds__(256) void pack_whh3(const float* __restrict__ Whh,
                                                 unsigned int* __restrict__ WhhP3) {
  int idx = blockIdx.x * 256 + threadIdx.x;  // 131072 u32 total
  int c = idx & 3;
  int g = (idx >> 2) & 127;
  int o = (idx >> 9) & 3;
  int k4 = idx >> 11;
  int p = k4 * 4 + c;        // f16-pair index 0..255
  int j = o * 128 + g;       // output column
  float f0 = Whh[(2 * p) * 512 + j];
  float f1 = Whh[(2 * p + 1) * 512 + j];
  WhhP3[idx] = pack_f16x2(f0, f1);
}

// ---------------------------------------------------------------------------
// Prep 2: Wo [h][v] f32 -> WoT [v][h] bf16
// ---------------------------------------------------------------------------
__global__ __launch_bounds__(256) void transpose_wo(const float* __restrict__ Wo,
                                                    unsigned short* __restrict__ WoT) {
  __shared__ float tile[64][65];
  const int tv = blockIdx.x;   // 0..63  (V/64)
  const int th = blockIdx.y;   // 0..7   (H/64)
  const int tid = threadIdx.x;
  const int c = tid & 63, r4 = tid >> 6;
#pragma unroll
  for (int p = 0; p < 16; ++p) {
    int hl = p * 4 + r4;
    tile[hl][c] = Wo[(size_t)(th * 64 + hl) * 4096 + tv * 64 + c];
  }
  __syncthreads();
#pragma unroll
  for (int p = 0; p < 16; ++p) {
    int vl = p * 4 + r4;
    WoT[(size_t)(tv * 64 + vl) * 512 + th * 64 + c] = f32_to_bf16(tile[c][vl]);
  }
}

// ---------------------------------------------------------------------------
// Recurrence v3. R5 post-mortem: LDS broadcast returns data at full lane rate
// (wave64 b128 = 1KB through 128B/cyc), so "every thread reads all of h" cost
// 4096 cyc/step -- the real bottleneck. Fix: 2D split. Thread (g=tid&127,
// i=tid>>7) computes 4 outputs {o*128+g} over k-slice i (128 h elems = 16
// uint4) -> h read once, reused 4x (LDS 128KB/step). Partials reduced via LDS.
// Weights: 32 uint4 resident (chunks 0-1) + chunks 2-3 streamed from L2
// through a named 16-uint4 buffer. amdgpu_waves_per_eu(2,2) pins the VGPR
// budget to 256 (R2-R5: allocator targeted higher occupancy and spilled).
// ---------------------------------------------------------------------------
#define LW(ch, o, q) W4[(((size_t)(i16 + (ch) * 4 + (q))) * 4 + (o)) * 128 + g]
#define LOADRW(o, ch, q) const uint4 w_##o##_##ch##_##q = LW(ch, o, q)

#define DOT4(A, W, H) do { A = fdot2_(W.x, H.x, A); A = fdot2_(W.y, H.y, A); \
                           A = fdot2_(W.z, H.z, A); A = fdot2_(W.w, H.w, A); } while (0)

#define DOTCH_O(ch, o, A) do { \
  DOT4(A, w_##o##_##ch##_0, h0_); DOT4(A, w_##o##_##ch##_1, h1_); \
  DOT4(A, w_##o##_##ch##_2, h2_); DOT4(A, w_##o##_##ch##_3, h3_); } while (0)

#define DOTCH_R(ch) do { \
  const uint4 h0_ = hb[i16 + ch * 4 + 0]; const uint4 h1_ = hb[i16 + ch * 4 + 1]; \
  const uint4 h2_ = hb[i16 + ch * 4 + 2]; const uint4 h3_ = hb[i16 + ch * 4 + 3]; \
  DOTCH_O(ch, 0, acc0); DOTCH_O(ch, 1, acc1); \
  DOTCH_O(ch, 2, acc2); DOTCH_O(ch, 3, acc3); } while (0)

#define DOTS_O(o, A) do { \
  DOT4(A, s_##o##_0, h0_); DOT4(A, s_##o##_1, h1_); \
  DOT4(A, s_##o##_2, h2_); DOT4(A, s_##o##_3, h3_); } while (0)

#define DOTCH_S(ch) do { \
  const uint4 h0_ = hb[i16 + ch * 4 + 0]; const uint4 h1_ = hb[i16 + ch * 4 + 1]; \
  const uint4 h2_ = hb[i16 + ch * 4 + 2]; const uint4 h3_ = hb[i16 + ch * 4 + 3]; \
  DOTS_O(0, acc0); DOTS_O(1, acc1); DOTS_O(2, acc2); DOTS_O(3, acc3); } while (0)

#define LOADS(ch) do { \
  s_0_0 = LW(ch, 0, 0); s_0_1 = LW(ch, 0, 1); s_0_2 = LW(ch, 0, 2); s_0_3 = LW(ch, 0, 3); \
  s_1_0 = LW(ch, 1, 0); s_1_1 = LW(ch, 1, 1); s_1_2 = LW(ch, 1, 2); s_1_3 = LW(ch, 1, 3); \
  s_2_0 = LW(ch, 2, 0); s_2_1 = LW(ch, 2, 1); s_2_2 = LW(ch, 2, 2); s_2_3 = LW(ch, 2, 3); \
  s_3_0 = LW(ch, 3, 0); s_3_1 = LW(ch, 3, 1); s_3_2 = LW(ch, 3, 2); s_3_3 = LW(ch, 3, 3); } while (0)

__global__ __launch_bounds__(512)
__attribute__((amdgpu_waves_per_eu(2, 2)))
void rnn_scan(const int* __restrict__ x,
              const float* Wxh,
              const unsigned int* WhhP3,
              const float* __restrict__ bh,
              unsigned short* hs) {
  __shared__ uint4 hbuf4[128];   // double-buffered h: 2 x 512 f16 values
  __shared__ float pbuf[2048];   // partial sums [i][j]
  __shared__ int toks[256];
  const int b = blockIdx.x;
  const int tid = threadIdx.x;
  const int g = tid & 127;       // output group
  const int i = tid >> 7;        // k-slice 0..3 (wave-uniform: 64 | 128)
  const int i16 = i * 16;
  const uint4* W4 = (const uint4*)WhhP3;

  // Register-resident weight chunks 0-1: 32 named uint4 (128 VGPR)
  LOADRW(0, 0, 0); LOADRW(0, 0, 1); LOADRW(0, 0, 2); LOADRW(0, 0, 3);
  LOADRW(1, 0, 0); LOADRW(1, 0, 1); LOADRW(1, 0, 2); LOADRW(1, 0, 3);
  LOADRW(2, 0, 0); LOADRW(2, 0, 1); LOADRW(2, 0, 2); LOADRW(2, 0, 3);
  LOADRW(3, 0, 0); LOADRW(3, 0, 1); LOADRW(3, 0, 2); LOADRW(3, 0, 3);
  LOADRW(0, 1, 0); LOADRW(0, 1, 1); LOADRW(0, 1, 2); LOADRW(0, 1, 3);
  LOADRW(1, 1, 0); LOADRW(1, 1, 1); LOADRW(1, 1, 2); LOADRW(1, 1, 3);
  LOADRW(2, 1, 0); LOADRW(2, 1, 1); LOADRW(2, 1, 2); LOADRW(2, 1, 3);
  LOADRW(3, 1, 0); LOADRW(3, 1, 1); LOADRW(3, 1, 2); LOADRW(3, 1, 3);

  if (tid < 64) hbuf4[tid] = make_uint4(0u, 0u, 0u, 0u);  // h0 = 0 (buf 0)
  if (tid < 256) toks[tid] = x[b * 256 + tid];
  const float bhj = bh[tid];   // thread tid reduces output j = tid
  __syncthreads();

  unsigned short* hb16all = (unsigned short*)hbuf4;  // [2][512] u16 view
  uint4 s_0_0, s_0_1, s_0_2, s_0_3, s_1_0, s_1_1, s_1_2, s_1_3;
  uint4 s_2_0, s_2_1, s_2_2, s_2_3, s_3_0, s_3_1, s_3_2, s_3_3;

  for (int t = 0; t < 256; ++t) {
    asm volatile("" ::: "memory");  // fence: no cross-iteration hoist of stream loads
    const int cur = t & 1;
    const uint4* hb = hbuf4 + cur * 64;
    const int tok = toks[t];

    LOADS(2);  // issue chunk-2 stream early; latency hides under resident dots
    const float xv = Wxh[(size_t)tok * 512 + tid];  // L2/L3-hot, coalesced

    float acc0 = 0.f, acc1 = 0.f, acc2 = 0.f, acc3 = 0.f;
    DOTCH_R(0);
    DOTCH_R(1);
    DOTCH_S(2);
    asm volatile("" ::: "memory");  // keep chunk-3 loads from inflating pressure above
    LOADS(3);
    DOTCH_S(3);

    // partials: pbuf[i][o*128+g]
    pbuf[i * 512 + 0 * 128 + g] = acc0;
    pbuf[i * 512 + 1 * 128 + g] = acc1;
    pbuf[i * 512 + 2 * 128 + g] = acc2;
    pbuf[i * 512 + 3 * 128 + g] = acc3;
    __syncthreads();

    // thread tid owns output j = tid: reduce 4 partials, tanh, store
    const float ssum = pbuf[tid] + pbuf[tid + 512] + pbuf[tid + 1024] + pbuf[tid + 1536];
    const float u_ = xv + ssum + bhj;
    const float h = tanhf(u_);
    hs[(size_t)(b * 256 + t) * 512 + tid] = f32_to_bf16(h);  // coalesced u16
    half2_t hp2 = __builtin_amdgcn_cvt_pkrtz(h, h);
    unsigned int hu = __builtin_bit_cast(unsigned int, hp2);
    hb16all[(cur ^ 1) * 512 + tid] = (unsigned short)(hu & 0xFFFFu);
    __syncthreads();  // next h buffer complete
  }
}

// ---------------------------------------------------------------------------
// Output GEMM: C[16384,4096] = A[16384,512](bf16) @ WoT^T + Bo.  m97 structure.
// ---------------------------------------------------------------------------
__global__ __launch_bounds__(256) void gemm_out(const unsigned short* __restrict__ A,
                                                const unsigned short* __restrict__ Bt,
                                                const float* __restrict__ Bo,
                                                float* __restrict__ C) {
  __shared__ alignas(16) unsigned short As[128 * 32];
  __shared__ alignas(16) unsigned short Bs[128 * 32];
  const int tid = threadIdx.x;
  const int lane = tid & 63, wid = tid >> 6;
  const int bn = blockIdx.x & 31, bm = blockIdx.x >> 5;
  const int wr = wid >> 1, wc = wid & 1;

  f32x4 acc[4][4] = {};

  const unsigned short* Ag = A + (size_t)(bm * 128 + (tid >> 2)) * 512 + (tid & 3) * 8;
  const unsigned short* Bg = Bt + (size_t)(bn * 128 + (tid >> 2)) * 512 + (tid & 3) * 8;
  char* AsW = (char*)As + wid * 1024;
  char* BsW = (char*)Bs + wid * 1024;

  const int laneRow = lane & 15;
  const int k0 = (lane >> 4) * 8;

  for (int kt = 0; kt < 16; ++kt) {
    __syncthreads();
    const unsigned short* a0 = Ag + kt * 32;
    const unsigned short* b0 = Bg + kt * 32;
    glds16(a0,            AsW);
    glds16(a0 + 64 * 512, AsW + 4096);
    glds16(b0,            BsW);
    glds16(b0 + 64 * 512, BsW + 4096);
    __syncthreads();

    short8 af[4], bf[4];
#pragma unroll
    for (int f = 0; f < 4; ++f)
      af[f] = *(const short8*)&As[(wr * 64 + f * 16 + laneRow) * 32 + k0];
#pragma unroll
    for (int f = 0; f < 4; ++f)
      bf[f] = *(const short8*)&Bs[(wc * 64 + f * 16 + laneRow) * 32 + k0];
#pragma unroll
    for (int fm = 0; fm < 4; ++fm)
#pragma unroll
      for (int fn = 0; fn < 4; ++fn)
        acc[fm][fn] = __builtin_amdgcn_mfma_f32_16x16x32_bf16(af[fm], bf[fn], acc[fm][fn], 0, 0, 0);
  }

  const int mg0 = bm * 128 + wr * 64, ng0 = bn * 128 + wc * 64;
#pragma unroll
  for (int fn = 0; fn < 4; ++fn) {
    const int col = ng0 + fn * 16 + laneRow;
    const float bo = Bo[col];
#pragma unroll
    for (int fm = 0; fm < 4; ++fm) {
      const int row0 = mg0 + fm * 16 + (lane >> 4) * 4;
#pragma unroll
      for (int r = 0; r < 4; ++r)
        C[(size_t)(row0 + r) * 4096 + col] = acc[fm][fn][r] + bo;
    }
  }
}

// ---------------------------------------------------------------------------
extern "C" void kernel_launch(void* const* d_in, const int* in_sizes, int n_in,
                              void* d_out, int out_size, void* d_ws, size_t ws_size,
                              hipStream_t stream) {
  (void)in_sizes; (void)n_in; (void)out_size; (void)ws_size;
  const int* x = (const int*)d_in[0];
  const float* Wxh = (const float*)d_in[1];
  const float* Whh = (const float*)d_in[2];
  const float* bh = (const float*)d_in[3];
  const float* Wo = (const float*)d_in[4];
  const float* Bo = (const float*)d_in[5];
  float* out = (float*)d_out;

  // workspace: WhhP3 512KB | WoT 4MB | hs 16MB  (total 20.5 MB)
  unsigned int* WhhP3 = (unsigned int*)d_ws;
  unsigned short* WoT = (unsigned short*)((char*)d_ws + (512u << 10));
  unsigned short* hs = (unsigned short*)((char*)d_ws + (512u << 10) + (4u << 20));

  hipLaunchKernelGGL(pack_whh3, dim3(512), dim3(256), 0, stream, Whh, WhhP3);
  hipLaunchKernelGGL(transpose_wo, dim3(64, 8), dim3(256), 0, stream, Wo, WoT);
  hipLaunchKernelGGL(rnn_scan, dim3(64), dim3(512), 0, stream, x, Wxh, WhhP3, bh, hs);
  hipLaunchKernelGGL(gemm_out, dim3(4096), dim3(256), 0, stream, hs, WoT, Bo, out);
}